// Round 3
// baseline (1559.647 us; speedup 1.0000x reference)
//
#include <hip/hip_runtime.h>
#include <math.h>

#define NPTS 262144
#define TP   16
#define NBLK (NPTS / TP)   // 16384 blocks
#define HDIM 128
#define HP   132   // padded leading dim: pt stride = 132 floats == bank offset 4 -> conflict-free

// channels: 0 primal, 1 d/dz, 2 d2/dz2, 3 d/dr, 4 d2/dr2

template<int K>
__device__ __forceinline__ void dense_layer(
    float sH[5][TP][HP],
    const float* __restrict__ W,   // K x 128 row-major
    const float* __restrict__ b,   // 128
    int pt, int cg)
{
    float acc[5][8];
#pragma unroll
    for (int c = 0; c < 5; ++c)
#pragma unroll
        for (int j = 0; j < 8; ++j) acc[c][j] = 0.f;

    const int col0 = cg * 8;
#pragma unroll 4
    for (int k = 0; k < K; ++k) {
        const float4 w0 = *reinterpret_cast<const float4*>(&W[k * HDIM + col0]);
        const float4 w1 = *reinterpret_cast<const float4*>(&W[k * HDIM + col0 + 4]);
        float h[5];
#pragma unroll
        for (int c = 0; c < 5; ++c) h[c] = sH[c][pt][k];
#pragma unroll
        for (int c = 0; c < 5; ++c) {
            acc[c][0] += h[c] * w0.x; acc[c][1] += h[c] * w0.y;
            acc[c][2] += h[c] * w0.z; acc[c][3] += h[c] * w0.w;
            acc[c][4] += h[c] * w1.x; acc[c][5] += h[c] * w1.y;
            acc[c][6] += h[c] * w1.z; acc[c][7] += h[c] * w1.w;
        }
    }
    __syncthreads();   // everyone done READING old sH
#pragma unroll
    for (int j = 0; j < 8; ++j) {
        float z   = acc[0][j] + b[col0 + j];
        float t   = tanhf(z);
        float s   = 1.f - t * t;
        float tz  = s * acc[1][j];
        float tzz = s * acc[2][j] - 2.f * t * tz * acc[1][j];
        float tr  = s * acc[3][j];
        float trr = s * acc[4][j] - 2.f * t * tr * acc[3][j];
        sH[0][pt][col0 + j] = t;
        sH[1][pt][col0 + j] = tz;
        sH[2][pt][col0 + j] = tzz;
        sH[3][pt][col0 + j] = tr;
        sH[4][pt][col0 + j] = trr;
    }
    __syncthreads();
}

__global__ __launch_bounds__(256) void pde_main(
    const float* __restrict__ X,    // N x 4
    const int*   __restrict__ fid,  // N
    const float* __restrict__ W1, const float* __restrict__ b1,
    const float* __restrict__ W2, const float* __restrict__ b2,
    const float* __restrict__ W3, const float* __restrict__ b3,
    const float* __restrict__ Wo, const float* __restrict__ bo,
    const float* __restrict__ emb, // 4 x 8
    float* __restrict__ partials)  // [NBLK][2]: sum eres^2, sum sres^2 per block
{
    __shared__ float sH[5][TP][HP];
    __shared__ float sO[5][TP][8];
    __shared__ float sRes[TP][2];

    const int tid = threadIdx.x;
    const int pt  = tid >> 4;   // 0..15
    const int cg  = tid & 15;   // 0..15
    const int p0  = blockIdx.x * TP;

    // ---- layer-0 input (12-dim): [x0..x3, emb0..emb7]; tangents e_z (dim1), e_r (dim2) ----
    for (int idx = tid; idx < 5 * TP * 12; idx += 256) {
        int k = idx % 12;
        int t = idx / 12;
        int p = t % TP;
        int c = t / TP;
        float v = 0.f;
        if (c == 0) {
            v = (k < 4) ? X[(p0 + p) * 4 + k] : emb[fid[p0 + p] * 8 + (k - 4)];
        } else if (c == 1) { v = (k == 1) ? 1.f : 0.f; }
        else if (c == 3)   { v = (k == 2) ? 1.f : 0.f; }
        sH[c][p][k] = v;
    }
    __syncthreads();

    dense_layer<12>(sH, W1, b1, pt, cg);
    dense_layer<HDIM>(sH, W2, b2, pt, cg);
    dense_layer<HDIM>(sH, W3, b3, pt, cg);

    // ---- output head: channel cg (cg<5), 7 outputs, K=128 ----
    if (cg < 5) {
        const int c = cg;
        float acc[7];
#pragma unroll
        for (int j = 0; j < 7; ++j) acc[j] = 0.f;
        for (int k = 0; k < HDIM; ++k) {
            float h = sH[c][pt][k];
#pragma unroll
            for (int j = 0; j < 7; ++j) acc[j] += h * Wo[k * 7 + j];
        }
#pragma unroll
        for (int j = 0; j < 7; ++j)
            sO[c][pt][j] = acc[j] + ((c == 0) ? bo[j] : 0.f);
    }
    __syncthreads();

    // ---- epilogue: one thread per point ----
    if (cg == 0) {
        float o0   = sO[0][pt][0], o1  = sO[0][pt][1];
        float o0z  = sO[1][pt][0], o1z = sO[1][pt][1];
        float o0zz = sO[2][pt][0];
        float o0r  = sO[3][pt][0];
        float o0rr = sO[4][pt][0];

        // T head
        float sg  = 1.f / (1.f + expf(-o0));
        float T   = 300.f + 2000.f * sg;
        float sp  = sg * (1.f - sg);          // sigma'
        float spp = sp * (1.f - 2.f * sg);    // sigma''
        float Tz  = 2000.f * sp * o0z;
        float Tzz = 2000.f * (spp * o0z * o0z + sp * o0zz);
        float Tr  = 2000.f * sp * o0r;
        float Trr = 2000.f * (spp * o0r * o0r + sp * o0rr);

        // fv head
        float fv  = ((o1 > 20.f) ? o1 : log1pf(expf(o1))) * 1e-6f;
        float s1  = 1.f / (1.f + expf(-o1));
        float fvz = s1 * o1z * 1e-6f;

        // softmax head (5 logits: o[2..6]); Y_prec = comp 3, Y_O2 = comp 4
        float y0 = sO[0][pt][2], y1 = sO[0][pt][3], y2 = sO[0][pt][4];
        float y3 = sO[0][pt][5], y4 = sO[0][pt][6];
        float m  = fmaxf(fmaxf(fmaxf(y0, y1), fmaxf(y2, y3)), y4);
        float e0 = expf(y0 - m), e1 = expf(y1 - m), e2 = expf(y2 - m);
        float e3 = expf(y3 - m), e4 = expf(y4 - m);
        float inv = 1.f / (e0 + e1 + e2 + e3 + e4);
        float Yp = e3 * inv;
        float Yo = e4 * inv;

        float r  = X[(p0 + pt) * 4 + 2];
        float rs = fmaxf(r, 1e-6f);
        float lap = Trr + Tr / rs;
        float eres = 180.f * Tz - 0.06f * lap - 0.06f * Tzz;   // RHO*CP*VZ=180, KT=0.06

        float nuc  = 1e4f * Yp * expf(-20000.f / T);
        float grow = 5e3f * Yp * fv * expf(-12000.f / T);
        float ox   = 1e5f * Yo * fv * sqrtf(T) * expf(-16000.f / T);
        float sres = 0.5f * fvz - nuc - grow + ox;

        sRes[pt][0] = eres * eres;
        sRes[pt][1] = sres * sres;
    }
    __syncthreads();
    if (tid == 0) {
        float se = 0.f, ss = 0.f;
#pragma unroll
        for (int p = 0; p < TP; ++p) { se += sRes[p][0]; ss += sRes[p][1]; }
        partials[2 * blockIdx.x]     = se;
        partials[2 * blockIdx.x + 1] = ss;
    }
}

__global__ __launch_bounds__(256) void pde_finalize(
    const float* __restrict__ partials, float* __restrict__ out)
{
    __shared__ double rE[256];
    __shared__ double rS[256];
    const int tid = threadIdx.x;
    double se = 0.0, ss = 0.0;
    for (int i = tid; i < NBLK; i += 256) {
        se += (double)partials[2 * i];
        ss += (double)partials[2 * i + 1];
    }
    rE[tid] = se; rS[tid] = ss;
    __syncthreads();
    for (int s = 128; s > 0; s >>= 1) {
        if (tid < s) { rE[tid] += rE[tid + s]; rS[tid] += rS[tid + s]; }
        __syncthreads();
    }
    if (tid == 0) {
        const double invN = 1.0 / (double)NPTS;
        float le = (float)(rE[0] * invN);
        float ls = (float)(rS[0] * invN);
        out[0] = le;
        out[1] = ls;
        out[2] = le + ls;
    }
}

extern "C" void kernel_launch(void* const* d_in, const int* in_sizes, int n_in,
                              void* d_out, int out_size, void* d_ws, size_t ws_size,
                              hipStream_t stream)
{
    const float* X   = (const float*)d_in[0];
    const int*   fid = (const int*)  d_in[1];
    const float* W1  = (const float*)d_in[2];
    const float* b1  = (const float*)d_in[3];
    const float* W2  = (const float*)d_in[4];
    const float* b2  = (const float*)d_in[5];
    const float* W3  = (const float*)d_in[6];
    const float* b3  = (const float*)d_in[7];
    const float* Wo  = (const float*)d_in[8];
    const float* bo  = (const float*)d_in[9];
    const float* emb = (const float*)d_in[10];

    float* partials = (float*)d_ws;   // NBLK * 2 floats = 128 KB
    float* out      = (float*)d_out;

    pde_main<<<NBLK, 256, 0, stream>>>(X, fid, W1, b1, W2, b2, W3, b3, Wo, bo, emb, partials);
    pde_finalize<<<1, 256, 0, stream>>>(partials, out);
}

// Round 4
// 407.209 us; speedup vs baseline: 3.8301x; 3.8301x over previous
//
#include <hip/hip_runtime.h>
#include <math.h>

#define NPTS 262144
#define PTS  32
#define NBLK (NPTS / PTS)   // 8192 blocks
#define AP   136            // activation pitch in f16 (272 B: 16B-aligned rows, conflict-free b128)
#define A1P  40             // layer-1 staging pitch in f16 (80 B)

typedef _Float16 f16;
typedef f16   f16x8 __attribute__((ext_vector_type(8)));
typedef float f32x4 __attribute__((ext_vector_type(4)));

// MFMA 16x16x32 f16 layouts (guide-verified):
//   A: lane holds A[m=lane&15][k=(lane>>4)*8 + j], j=0..7  (8 f16, contiguous k)
//   B: lane holds B[k=(lane>>4)*8 + j][n=lane&15]          (store W transposed: Wt[n][k])
//   C: lane holds D[row=(lane>>4)*4 + reg][col=lane&15], reg=0..3

__global__ void prep_weights(const float* __restrict__ W1, const float* __restrict__ W2,
                             const float* __restrict__ W3, const float* __restrict__ Wo,
                             f16* __restrict__ wt1, f16* __restrict__ wt2,
                             f16* __restrict__ wt3, f16* __restrict__ wot)
{
    int tid    = blockIdx.x * blockDim.x + threadIdx.x;
    int stride = gridDim.x * blockDim.x;
    // Wt1: [128 n][32 k]  (K padded 12->32 with zeros)
    for (int i = tid; i < 128 * 32; i += stride) {
        int n = i >> 5, k = i & 31;
        wt1[i] = (f16)((k < 12) ? W1[k * 128 + n] : 0.f);
    }
    // Wt2/Wt3: [128 n][128 k]
    for (int i = tid; i < 128 * 128; i += stride) {
        int n = i >> 7, k = i & 127;
        wt2[i] = (f16)W2[k * 128 + n];
        wt3[i] = (f16)W3[k * 128 + n];
    }
    // Wot: [16 n][128 k]  (7 real output cols, rest zero)
    for (int i = tid; i < 16 * 128; i += stride) {
        int n = i >> 7, k = i & 127;
        wot[i] = (f16)((n < 7) ? Wo[k * 7 + n] : 0.f);
    }
}

__device__ __forceinline__ void tanh_transform_store(
    f16 (*sAct)[PTS][AP], const f32x4 acc[5], float bv,
    int rowbase, int q, int coln)
{
#pragma unroll
    for (int r = 0; r < 4; ++r) {
        int row = rowbase + q * 4 + r;
        float z  = acc[0][r] + bv;
        float t  = tanhf(z);
        float s  = 1.f - t * t;
        float a1 = acc[1][r], a2 = acc[2][r], a3 = acc[3][r], a4 = acc[4][r];
        float tz  = s * a1;
        float tzz = s * a2 - 2.f * t * tz * a1;
        float tr  = s * a3;
        float trr = s * a4 - 2.f * t * tr * a3;
        sAct[0][row][coln] = (f16)t;
        sAct[1][row][coln] = (f16)tz;
        sAct[2][row][coln] = (f16)tzz;
        sAct[3][row][coln] = (f16)tr;
        sAct[4][row][coln] = (f16)trr;
    }
}

__device__ __forceinline__ void layer128(
    f16 (*sAct)[PTS][AP], const f16* __restrict__ Wt, const float* __restrict__ b,
    int rowbase, int half, int q, int m)
{
    // A-frags for this wave's rowtile: 5 ch x 4 ktiles, kept in registers
    f16x8 A[5][4];
#pragma unroll
    for (int c = 0; c < 5; ++c)
#pragma unroll
        for (int kt = 0; kt < 4; ++kt)
            A[c][kt] = *(const f16x8*)&sAct[c][rowbase + m][kt * 32 + q * 8];
    __syncthreads();   // all waves have their A in regs; safe to overwrite sAct

#pragma unroll
    for (int ct0 = 0; ct0 < 4; ++ct0) {
        const int ct   = half * 4 + ct0;
        const int coln = ct * 16 + m;
        // prefetch the 4 B-frags for this coltile (global, L1/L2-resident)
        f16x8 B0 = *(const f16x8*)&Wt[coln * 128 +   0 + q * 8];
        f16x8 B1 = *(const f16x8*)&Wt[coln * 128 +  32 + q * 8];
        f16x8 B2 = *(const f16x8*)&Wt[coln * 128 +  64 + q * 8];
        f16x8 B3 = *(const f16x8*)&Wt[coln * 128 +  96 + q * 8];
        f32x4 acc[5];
#pragma unroll
        for (int c = 0; c < 5; ++c) acc[c] = (f32x4){0.f, 0.f, 0.f, 0.f};
#pragma unroll
        for (int c = 0; c < 5; ++c) acc[c] = __builtin_amdgcn_mfma_f32_16x16x32_f16(A[c][0], B0, acc[c], 0, 0, 0);
#pragma unroll
        for (int c = 0; c < 5; ++c) acc[c] = __builtin_amdgcn_mfma_f32_16x16x32_f16(A[c][1], B1, acc[c], 0, 0, 0);
#pragma unroll
        for (int c = 0; c < 5; ++c) acc[c] = __builtin_amdgcn_mfma_f32_16x16x32_f16(A[c][2], B2, acc[c], 0, 0, 0);
#pragma unroll
        for (int c = 0; c < 5; ++c) acc[c] = __builtin_amdgcn_mfma_f32_16x16x32_f16(A[c][3], B3, acc[c], 0, 0, 0);

        tanh_transform_store(sAct, acc, b[coln], rowbase, q, coln);
    }
    __syncthreads();   // layer output visible to all
}

__global__ __launch_bounds__(256) void pde_main(
    const float* __restrict__ X,    // N x 4
    const int*   __restrict__ fid,  // N
    const float* __restrict__ emb,  // 4 x 8
    const float* __restrict__ b1, const float* __restrict__ b2,
    const float* __restrict__ b3, const float* __restrict__ bo,
    const f16* __restrict__ Wt1, const f16* __restrict__ Wt2,
    const f16* __restrict__ Wt3, const f16* __restrict__ Wot,
    float* __restrict__ partials)   // [NBLK][2]
{
    __shared__ f16   sAct[5][PTS][AP];   // 43520 B
    __shared__ f16   sA1[5][PTS][A1P];   // 12800 B
    __shared__ float sO[5][PTS][8];      //  5120 B
    __shared__ float sRes[PTS][2];

    const int tid     = threadIdx.x;
    const int w       = tid >> 6;     // wave 0..3
    const int lane    = tid & 63;
    const int q       = lane >> 4;    // quad 0..3
    const int m       = lane & 15;    // A row / B col / C col
    const int rt      = w & 1;        // rowtile (16 pts)
    const int half    = w >> 1;       // column half (4 coltiles)
    const int rowbase = rt * 16;
    const int p0      = blockIdx.x * PTS;

    // ---- stage layer-1 input: [x0..x3, emb0..7, 0-pad]; tangent rows e_z (c=1), e_r (c=3) ----
    for (int idx = tid; idx < 5 * PTS * 32; idx += 256) {
        int k = idx & 31;
        int p = (idx >> 5) & (PTS - 1);
        int c = idx >> 10;
        float v = 0.f;
        if (c == 0) {
            if (k < 4)       v = X[(p0 + p) * 4 + k];
            else if (k < 12) v = emb[fid[p0 + p] * 8 + (k - 4)];
        } else if (c == 1) { v = (k == 1) ? 1.f : 0.f; }
        else if (c == 3)   { v = (k == 2) ? 1.f : 0.f; }
        sA1[c][p][k] = (f16)v;
    }
    __syncthreads();

    // ---- layer 1: K=32 (12 real), output -> sAct ----
    {
        f16x8 A[5];
#pragma unroll
        for (int c = 0; c < 5; ++c)
            A[c] = *(const f16x8*)&sA1[c][rowbase + m][q * 8];
#pragma unroll
        for (int ct0 = 0; ct0 < 4; ++ct0) {
            const int ct   = half * 4 + ct0;
            const int coln = ct * 16 + m;
            f16x8 B = *(const f16x8*)&Wt1[coln * 32 + q * 8];
            f32x4 acc[5];
#pragma unroll
            for (int c = 0; c < 5; ++c) {
                acc[c] = (f32x4){0.f, 0.f, 0.f, 0.f};
                acc[c] = __builtin_amdgcn_mfma_f32_16x16x32_f16(A[c], B, acc[c], 0, 0, 0);
            }
            tanh_transform_store(sAct, acc, b1[coln], rowbase, q, coln);
        }
        __syncthreads();
    }

    // ---- layers 2, 3 ----
    layer128(sAct, Wt2, b2, rowbase, half, q, m);
    layer128(sAct, Wt3, b3, rowbase, half, q, m);

    // ---- output head: 7 cols (padded 16), only colhalf-0 waves ----
    if (half == 0) {
        f16x8 A[5][4];
#pragma unroll
        for (int c = 0; c < 5; ++c)
#pragma unroll
            for (int kt = 0; kt < 4; ++kt)
                A[c][kt] = *(const f16x8*)&sAct[c][rowbase + m][kt * 32 + q * 8];
        f32x4 acc[5];
#pragma unroll
        for (int c = 0; c < 5; ++c) acc[c] = (f32x4){0.f, 0.f, 0.f, 0.f};
#pragma unroll
        for (int kt = 0; kt < 4; ++kt) {
            f16x8 B = *(const f16x8*)&Wot[m * 128 + kt * 32 + q * 8];
#pragma unroll
            for (int c = 0; c < 5; ++c)
                acc[c] = __builtin_amdgcn_mfma_f32_16x16x32_f16(A[c][kt], B, acc[c], 0, 0, 0);
        }
        if (m < 7) {
#pragma unroll
            for (int c = 0; c < 5; ++c)
#pragma unroll
                for (int r = 0; r < 4; ++r)
                    sO[c][rowbase + q * 4 + r][m] = acc[c][r] + ((c == 0) ? bo[m] : 0.f);
        }
    }
    __syncthreads();

    // ---- residual epilogue: one thread per point ----
    if (tid < PTS) {
        const int pt = tid;
        float o0   = sO[0][pt][0], o1  = sO[0][pt][1];
        float o0z  = sO[1][pt][0], o1z = sO[1][pt][1];
        float o0zz = sO[2][pt][0];
        float o0r  = sO[3][pt][0];
        float o0rr = sO[4][pt][0];

        float sg  = 1.f / (1.f + expf(-o0));
        float T   = 300.f + 2000.f * sg;
        float sp  = sg * (1.f - sg);
        float spp = sp * (1.f - 2.f * sg);
        float Tz  = 2000.f * sp * o0z;
        float Tzz = 2000.f * (spp * o0z * o0z + sp * o0zz);
        float Tr  = 2000.f * sp * o0r;
        float Trr = 2000.f * (spp * o0r * o0r + sp * o0rr);

        float fv  = ((o1 > 20.f) ? o1 : log1pf(expf(o1))) * 1e-6f;
        float s1  = 1.f / (1.f + expf(-o1));
        float fvz = s1 * o1z * 1e-6f;

        float y0 = sO[0][pt][2], y1 = sO[0][pt][3], y2 = sO[0][pt][4];
        float y3 = sO[0][pt][5], y4 = sO[0][pt][6];
        float mx = fmaxf(fmaxf(fmaxf(y0, y1), fmaxf(y2, y3)), y4);
        float e0 = expf(y0 - mx), e1 = expf(y1 - mx), e2 = expf(y2 - mx);
        float e3 = expf(y3 - mx), e4 = expf(y4 - mx);
        float inv = 1.f / (e0 + e1 + e2 + e3 + e4);
        float Yp = e3 * inv;
        float Yo = e4 * inv;

        float r  = X[(p0 + pt) * 4 + 2];
        float rs = fmaxf(r, 1e-6f);
        float lap = Trr + Tr / rs;
        float eres = 180.f * Tz - 0.06f * lap - 0.06f * Tzz;

        float nuc  = 1e4f * Yp * expf(-20000.f / T);
        float grow = 5e3f * Yp * fv * expf(-12000.f / T);
        float ox   = 1e5f * Yo * fv * sqrtf(T) * expf(-16000.f / T);
        float sres = 0.5f * fvz - nuc - grow + ox;

        sRes[pt][0] = eres * eres;
        sRes[pt][1] = sres * sres;
    }
    __syncthreads();
    if (tid == 0) {
        float se = 0.f, ss = 0.f;
#pragma unroll
        for (int p = 0; p < PTS; ++p) { se += sRes[p][0]; ss += sRes[p][1]; }
        partials[2 * blockIdx.x]     = se;
        partials[2 * blockIdx.x + 1] = ss;
    }
}

__global__ __launch_bounds__(256) void pde_finalize(
    const float* __restrict__ partials, float* __restrict__ out)
{
    __shared__ double rE[256];
    __shared__ double rS[256];
    const int tid = threadIdx.x;
    double se = 0.0, ss = 0.0;
    for (int i = tid; i < NBLK; i += 256) {
        se += (double)partials[2 * i];
        ss += (double)partials[2 * i + 1];
    }
    rE[tid] = se; rS[tid] = ss;
    __syncthreads();
    for (int s = 128; s > 0; s >>= 1) {
        if (tid < s) { rE[tid] += rE[tid + s]; rS[tid] += rS[tid + s]; }
        __syncthreads();
    }
    if (tid == 0) {
        const double invN = 1.0 / (double)NPTS;
        float le = (float)(rE[0] * invN);
        float ls = (float)(rS[0] * invN);
        out[0] = le;
        out[1] = ls;
        out[2] = le + ls;
    }
}

extern "C" void kernel_launch(void* const* d_in, const int* in_sizes, int n_in,
                              void* d_out, int out_size, void* d_ws, size_t ws_size,
                              hipStream_t stream)
{
    const float* X   = (const float*)d_in[0];
    const int*   fid = (const int*)  d_in[1];
    const float* W1  = (const float*)d_in[2];
    const float* b1  = (const float*)d_in[3];
    const float* W2  = (const float*)d_in[4];
    const float* b2  = (const float*)d_in[5];
    const float* W3  = (const float*)d_in[6];
    const float* b3  = (const float*)d_in[7];
    const float* Wo  = (const float*)d_in[8];
    const float* bo  = (const float*)d_in[9];
    const float* emb = (const float*)d_in[10];

    f16* wt1 = (f16*)d_ws;              // 128*32
    f16* wt2 = wt1 + 128 * 32;          // 128*128
    f16* wt3 = wt2 + 128 * 128;         // 128*128
    f16* wot = wt3 + 128 * 128;         // 16*128
    float* partials = (float*)(wot + 16 * 128);   // NBLK*2 floats
    float* out      = (float*)d_out;

    prep_weights<<<64, 256, 0, stream>>>(W1, W2, W3, Wo, wt1, wt2, wt3, wot);
    pde_main<<<NBLK, 256, 0, stream>>>(X, fid, emb, b1, b2, b3, bo,
                                       wt1, wt2, wt3, wot, partials);
    pde_finalize<<<1, 256, 0, stream>>>(partials, out);
}

// Round 7
// 294.215 us; speedup vs baseline: 5.3010x; 1.3841x over previous
//
#include <hip/hip_runtime.h>
#include <math.h>

#define NPTS 262144
#define PTS  32
#define NBLK (NPTS / PTS)   // 8192 blocks
#define AP   136            // activation pitch in f16 (272 B: 16B-aligned rows, 2-way-conflict-free b128)

typedef _Float16 f16;
typedef f16   f16x8 __attribute__((ext_vector_type(8)));
typedef float f32x4 __attribute__((ext_vector_type(4)));

// MFMA 16x16x32 f16 layouts (guide-verified):
//   A: lane holds A[m=lane&15][k=(lane>>4)*8 + j], j=0..7  (8 f16, contiguous k)
//   B: lane holds B[k=(lane>>4)*8 + j][n=lane&15]          (store W transposed: Wt[n][k])
//   C: lane holds D[row=(lane>>4)*4 + reg][col=lane&15], reg=0..3

__device__ __forceinline__ float fast_tanh(float z) {
    // tanh(z) = 1 - 2/(e^{2z}+1); v_exp_f32-based, ~10 instrs vs ~50 for libm tanhf
    float e = __expf(2.f * z);       // inf for large z -> t=1; 0 for very neg -> t=-1
    return 1.f - 2.f / (e + 1.f);
}

__global__ void prep_weights(const float* __restrict__ W1, const float* __restrict__ W2,
                             const float* __restrict__ W3, const float* __restrict__ Wo,
                             f16* __restrict__ wt1, f16* __restrict__ wt2,
                             f16* __restrict__ wt3, f16* __restrict__ wot)
{
    int tid    = blockIdx.x * blockDim.x + threadIdx.x;
    int stride = gridDim.x * blockDim.x;
    // Wt1: [128 n][32 k]  (K padded 12->32 with zeros)
    for (int i = tid; i < 128 * 32; i += stride) {
        int n = i >> 5, k = i & 31;
        wt1[i] = (f16)((k < 12) ? W1[k * 128 + n] : 0.f);
    }
    // Wt2/Wt3: [128 n][128 k]
    for (int i = tid; i < 128 * 128; i += stride) {
        int n = i >> 7, k = i & 127;
        wt2[i] = (f16)W2[k * 128 + n];
        wt3[i] = (f16)W3[k * 128 + n];
    }
    // Wot: [16 n][128 k]  (7 real output cols, rest zero)
    for (int i = tid; i < 16 * 128; i += stride) {
        int n = i >> 7, k = i & 127;
        wot[i] = (f16)((n < 7) ? Wo[k * 7 + n] : 0.f);
    }
}

__device__ __forceinline__ void tanh_transform_store(
    f16 (*sAct)[PTS][AP], const f32x4 acc[5], float bv,
    int rowbase, int q, int coln)
{
#pragma unroll
    for (int r = 0; r < 4; ++r) {
        int row = rowbase + q * 4 + r;
        float z  = acc[0][r] + bv;
        float t  = fast_tanh(z);
        float s  = 1.f - t * t;
        float a1 = acc[1][r], a2 = acc[2][r], a3 = acc[3][r], a4 = acc[4][r];
        float tz  = s * a1;
        float tzz = s * a2 - 2.f * t * tz * a1;
        float tr  = s * a3;
        float trr = s * a4 - 2.f * t * tr * a3;
        sAct[0][row][coln] = (f16)t;
        sAct[1][row][coln] = (f16)tz;
        sAct[2][row][coln] = (f16)tzz;
        sAct[3][row][coln] = (f16)tr;
        sAct[4][row][coln] = (f16)trr;
    }
}

__device__ __forceinline__ void layer128(
    f16 (*sAct)[PTS][AP], const f16* __restrict__ Wt, const float* __restrict__ b,
    int rowbase, int half, int q, int m)
{
    // A-frags for this wave's rowtile: 5 ch x 4 ktiles, kept in registers
    f16x8 A[5][4];
#pragma unroll
    for (int c = 0; c < 5; ++c)
#pragma unroll
        for (int kt = 0; kt < 4; ++kt)
            A[c][kt] = *(const f16x8*)&sAct[c][rowbase + m][kt * 32 + q * 8];
    __syncthreads();   // all waves have their A in regs; safe to overwrite sAct

#pragma unroll
    for (int ct0 = 0; ct0 < 4; ++ct0) {
        const int ct   = half * 4 + ct0;
        const int coln = ct * 16 + m;
        // prefetch the 4 B-frags for this coltile (global, L1/L2-resident)
        f16x8 B0 = *(const f16x8*)&Wt[coln * 128 +   0 + q * 8];
        f16x8 B1 = *(const f16x8*)&Wt[coln * 128 +  32 + q * 8];
        f16x8 B2 = *(const f16x8*)&Wt[coln * 128 +  64 + q * 8];
        f16x8 B3 = *(const f16x8*)&Wt[coln * 128 +  96 + q * 8];
        f32x4 acc[5];
#pragma unroll
        for (int c = 0; c < 5; ++c) acc[c] = (f32x4){0.f, 0.f, 0.f, 0.f};
#pragma unroll
        for (int c = 0; c < 5; ++c) acc[c] = __builtin_amdgcn_mfma_f32_16x16x32_f16(A[c][0], B0, acc[c], 0, 0, 0);
#pragma unroll
        for (int c = 0; c < 5; ++c) acc[c] = __builtin_amdgcn_mfma_f32_16x16x32_f16(A[c][1], B1, acc[c], 0, 0, 0);
#pragma unroll
        for (int c = 0; c < 5; ++c) acc[c] = __builtin_amdgcn_mfma_f32_16x16x32_f16(A[c][2], B2, acc[c], 0, 0, 0);
#pragma unroll
        for (int c = 0; c < 5; ++c) acc[c] = __builtin_amdgcn_mfma_f32_16x16x32_f16(A[c][3], B3, acc[c], 0, 0, 0);

        tanh_transform_store(sAct, acc, b[coln], rowbase, q, coln);
    }
    __syncthreads();   // layer output visible to all
}

__global__ __launch_bounds__(256, 3) void pde_main(
    const float* __restrict__ X,    // N x 4
    const int*   __restrict__ fid,  // N
    const float* __restrict__ emb,  // 4 x 8
    const float* __restrict__ b1, const float* __restrict__ b2,
    const float* __restrict__ b3, const float* __restrict__ bo,
    const f16* __restrict__ Wt1, const f16* __restrict__ Wt2,
    const f16* __restrict__ Wt3, const f16* __restrict__ Wot,
    float* __restrict__ partials)   // [NBLK][2]
{
    __shared__ f16   sAct[5][PTS][AP];   // 43520 B  (layer-1 input staged in cols 0..31)
    __shared__ float sO[5][PTS][8];      //  5120 B
    __shared__ float sRes[PTS][2];

    const int tid     = threadIdx.x;
    const int w       = tid >> 6;     // wave 0..3
    const int lane    = tid & 63;
    const int q       = lane >> 4;    // quad 0..3
    const int m       = lane & 15;    // A row / B col / C col
    const int rt      = w & 1;        // rowtile (16 pts)
    const int half    = w >> 1;       // column half (4 coltiles)
    const int rowbase = rt * 16;
    const int p0      = blockIdx.x * PTS;

    // ---- stage layer-1 input into sAct[..][..][0..31]: [x0..x3, emb0..7, 0-pad];
    //      tangent rows e_z (c=1), e_r (c=3) ----
    for (int idx = tid; idx < 5 * PTS * 32; idx += 256) {
        int k = idx & 31;
        int p = (idx >> 5) & (PTS - 1);
        int c = idx >> 10;
        float v = 0.f;
        if (c == 0) {
            if (k < 4)       v = X[(p0 + p) * 4 + k];
            else if (k < 12) v = emb[fid[p0 + p] * 8 + (k - 4)];
        } else if (c == 1) { v = (k == 1) ? 1.f : 0.f; }
        else if (c == 3)   { v = (k == 2) ? 1.f : 0.f; }
        sAct[c][p][k] = (f16)v;
    }
    __syncthreads();

    // ---- layer 1: K=32 (12 real), in-place sAct -> sAct ----
    {
        f16x8 A[5];
#pragma unroll
        for (int c = 0; c < 5; ++c)
            A[c] = *(const f16x8*)&sAct[c][rowbase + m][q * 8];
        __syncthreads();   // A-frags in regs; safe to overwrite staging cols
#pragma unroll
        for (int ct0 = 0; ct0 < 4; ++ct0) {
            const int ct   = half * 4 + ct0;
            const int coln = ct * 16 + m;
            f16x8 B = *(const f16x8*)&Wt1[coln * 32 + q * 8];
            f32x4 acc[5];
#pragma unroll
            for (int c = 0; c < 5; ++c) {
                acc[c] = (f32x4){0.f, 0.f, 0.f, 0.f};
                acc[c] = __builtin_amdgcn_mfma_f32_16x16x32_f16(A[c], B, acc[c], 0, 0, 0);
            }
            tanh_transform_store(sAct, acc, b1[coln], rowbase, q, coln);
        }
        __syncthreads();
    }

    // ---- layers 2, 3 ----
    layer128(sAct, Wt2, b2, rowbase, half, q, m);
    layer128(sAct, Wt3, b3, rowbase, half, q, m);

    // ---- output head: 7 cols (padded 16), only colhalf-0 waves ----
    if (half == 0) {
        f16x8 A[5][4];
#pragma unroll
        for (int c = 0; c < 5; ++c)
#pragma unroll
            for (int kt = 0; kt < 4; ++kt)
                A[c][kt] = *(const f16x8*)&sAct[c][rowbase + m][kt * 32 + q * 8];
        f32x4 acc[5];
#pragma unroll
        for (int c = 0; c < 5; ++c) acc[c] = (f32x4){0.f, 0.f, 0.f, 0.f};
#pragma unroll
        for (int kt = 0; kt < 4; ++kt) {
            f16x8 B = *(const f16x8*)&Wot[m * 128 + kt * 32 + q * 8];
#pragma unroll
            for (int c = 0; c < 5; ++c)
                acc[c] = __builtin_amdgcn_mfma_f32_16x16x32_f16(A[c][kt], B, acc[c], 0, 0, 0);
        }
        if (m < 7) {
#pragma unroll
            for (int c = 0; c < 5; ++c)
#pragma unroll
                for (int r = 0; r < 4; ++r)
                    sO[c][rowbase + q * 4 + r][m] = acc[c][r] + ((c == 0) ? bo[m] : 0.f);
        }
    }
    __syncthreads();

    // ---- residual epilogue: one thread per point ----
    if (tid < PTS) {
        const int pt = tid;
        float o0   = sO[0][pt][0], o1  = sO[0][pt][1];
        float o0z  = sO[1][pt][0], o1z = sO[1][pt][1];
        float o0zz = sO[2][pt][0];
        float o0r  = sO[3][pt][0];
        float o0rr = sO[4][pt][0];

        float sg  = 1.f / (1.f + __expf(-o0));
        float T   = 300.f + 2000.f * sg;
        float sp  = sg * (1.f - sg);
        float spp = sp * (1.f - 2.f * sg);
        float Tz  = 2000.f * sp * o0z;
        float Tzz = 2000.f * (spp * o0z * o0z + sp * o0zz);
        float Tr  = 2000.f * sp * o0r;
        float Trr = 2000.f * (spp * o0r * o0r + sp * o0rr);

        float fv  = ((o1 > 20.f) ? o1 : __logf(1.f + __expf(o1))) * 1e-6f;
        float s1  = 1.f / (1.f + __expf(-o1));
        float fvz = s1 * o1z * 1e-6f;

        float y0 = sO[0][pt][2], y1 = sO[0][pt][3], y2 = sO[0][pt][4];
        float y3 = sO[0][pt][5], y4 = sO[0][pt][6];
        float mx = fmaxf(fmaxf(fmaxf(y0, y1), fmaxf(y2, y3)), y4);
        float e0 = __expf(y0 - mx), e1 = __expf(y1 - mx), e2 = __expf(y2 - mx);
        float e3 = __expf(y3 - mx), e4 = __expf(y4 - mx);
        float inv = 1.f / (e0 + e1 + e2 + e3 + e4);
        float Yp = e3 * inv;
        float Yo = e4 * inv;

        float r  = X[(p0 + pt) * 4 + 2];
        float rs = fmaxf(r, 1e-6f);
        float lap = Trr + Tr / rs;
        float eres = 180.f * Tz - 0.06f * lap - 0.06f * Tzz;

        float nuc  = 1e4f * Yp * __expf(-20000.f / T);
        float grow = 5e3f * Yp * fv * __expf(-12000.f / T);
        float ox   = 1e5f * Yo * fv * sqrtf(T) * __expf(-16000.f / T);
        float sres = 0.5f * fvz - nuc - grow + ox;

        sRes[pt][0] = eres * eres;
        sRes[pt][1] = sres * sres;
    }
    __syncthreads();
    if (tid == 0) {
        float se = 0.f, ss = 0.f;
#pragma unroll
        for (int p = 0; p < PTS; ++p) { se += sRes[p][0]; ss += sRes[p][1]; }
        partials[2 * blockIdx.x]     = se;
        partials[2 * blockIdx.x + 1] = ss;
    }
}

__global__ __launch_bounds__(256) void pde_finalize(
    const float* __restrict__ partials, float* __restrict__ out)
{
    __shared__ double rE[256];
    __shared__ double rS[256];
    const int tid = threadIdx.x;
    const float2* p2 = (const float2*)partials;
    double se = 0.0, ss = 0.0;
    for (int i = tid; i < NBLK; i += 256) {
        float2 v = p2[i];
        se += (double)v.x;
        ss += (double)v.y;
    }
    rE[tid] = se; rS[tid] = ss;
    __syncthreads();
    for (int s = 128; s > 0; s >>= 1) {
        if (tid < s) { rE[tid] += rE[tid + s]; rS[tid] += rS[tid + s]; }
        __syncthreads();
    }
    if (tid == 0) {
        const double invN = 1.0 / (double)NPTS;
        float le = (float)(rE[0] * invN);
        float ls = (float)(rS[0] * invN);
        out[0] = le;
        out[1] = ls;
        out[2] = le + ls;
    }
}

extern "C" void kernel_launch(void* const* d_in, const int* in_sizes, int n_in,
                              void* d_out, int out_size, void* d_ws, size_t ws_size,
                              hipStream_t stream)
{
    const float* X   = (const float*)d_in[0];
    const int*   fid = (const int*)  d_in[1];
    const float* W1  = (const float*)d_in[2];
    const float* b1  = (const float*)d_in[3];
    const float* W2  = (const float*)d_in[4];
    const float* b2  = (const float*)d_in[5];
    const float* W3  = (const float*)d_in[6];
    const float* b3  = (const float*)d_in[7];
    const float* Wo  = (const float*)d_in[8];
    const float* bo  = (const float*)d_in[9];
    const float* emb = (const float*)d_in[10];

    f16* wt1 = (f16*)d_ws;              // 128*32
    f16* wt2 = wt1 + 128 * 32;          // 128*128
    f16* wt3 = wt2 + 128 * 128;         // 128*128
    f16* wot = wt3 + 128 * 128;         // 16*128
    float* partials = (float*)(wot + 16 * 128);   // NBLK*2 floats
    float* out      = (float*)d_out;

    prep_weights<<<64, 256, 0, stream>>>(W1, W2, W3, Wo, wt1, wt2, wt3, wot);
    pde_main<<<NBLK, 256, 0, stream>>>(X, fid, emb, b1, b2, b3, bo,
                                       wt1, wt2, wt3, wot, partials);
    pde_finalize<<<1, 256, 0, stream>>>(partials, out);
}